// Round 1
// baseline (1972.754 us; speedup 1.0000x reference)
//
#include <hip/hip_runtime.h>
#include <hip/hip_bf16.h>

#define N_NODES 50000
#define E_EDGES 200000
static constexpr float INV_SQRT_C = 0.08838834764831845f; // 1/sqrt(128)

typedef __attribute__((ext_vector_type(4))) float f32x4;
typedef __attribute__((ext_vector_type(8))) short s16x8;
typedef __attribute__((ext_vector_type(4))) short s16x4;

__device__ __forceinline__ float b2f(unsigned short u) {
  union { unsigned u; float f; } x; x.u = ((unsigned)u) << 16; return x.f;
}
__device__ __forceinline__ short f2b(float f) {
  union { float f; unsigned u; } x; x.f = f;
  unsigned r = x.u + 0x7FFFu + ((x.u >> 16) & 1u);  // RNE
  return (short)(r >> 16);
}

struct WPtrs { const float* w[10]; };

// Transpose + convert 10 [256x256] f32 row-major (k-major) weights to
// bf16 col-major: out[c*256 + k] = W[k][c]
__global__ __launch_bounds__(256) void prep_transpose(WPtrs p, short* __restrict__ out) {
  const float* w = p.w[blockIdx.x];
  short* o = out + (size_t)blockIdx.x * 65536;
  for (int idx = threadIdx.x; idx < 65536; idx += 256) {
    int k = idx >> 8, c = idx & 255;
    o[c * 256 + k] = f2b(w[idx]);
  }
}

// C[M,256] = X[M,256] @ W[256,256] + b for two weight matrices sharing the
// staged X tile. Output either bf16 table (o16) or f32 (of).
__global__ __launch_bounds__(256) void node_gemm(
    const float* __restrict__ X, int M,
    const short* __restrict__ Wt0, const float* __restrict__ bias0,
    unsigned short* __restrict__ o16_0, float* __restrict__ of0,
    const short* __restrict__ Wt1, const float* __restrict__ bias1,
    unsigned short* __restrict__ o16_1, float* __restrict__ of1)
{
  __shared__ short As[64 * 264];          // bf16 bits, row stride 264 (=528B, 16B-aligned, pads banks)
  const int tid = threadIdx.x;
  const int l = tid & 63;
  const int w = tid >> 6;
  const long m0 = (long)blockIdx.x * 64;

  { // stage 64 rows of X -> bf16 LDS
    const int j4 = tid & 63;              // col group (4 floats)
    const int rb = tid >> 6;
#pragma unroll
    for (int i = 0; i < 16; ++i) {
      int r = rb + i * 4;
      long node = m0 + r;
      float4 xv = make_float4(0.f, 0.f, 0.f, 0.f);
      if (node < M) xv = *(const float4*)(X + node * 256 + j4 * 4);
      s16x4 sv; sv[0] = f2b(xv.x); sv[1] = f2b(xv.y); sv[2] = f2b(xv.z); sv[3] = f2b(xv.w);
      *(s16x4*)&As[r * 264 + j4 * 4] = sv;
    }
  }
  __syncthreads();

  const int arow = 16 * w + (l & 15);
  const int koff = (l >> 4) * 8;
  const int colb = l & 15;

#pragma unroll 1
  for (int job = 0; job < 2; ++job) {
    const short* Wt = job ? Wt1 : Wt0;
    const float* bias = job ? bias1 : bias0;
    unsigned short* o16 = job ? o16_1 : o16_0;
    float* of = job ? of1 : of0;

    f32x4 acc[16];
#pragma unroll
    for (int ct = 0; ct < 16; ++ct) acc[ct] = (f32x4)(0.0f);
#pragma unroll
    for (int ks = 0; ks < 8; ++ks) {
      s16x8 a = *(const s16x8*)&As[arow * 264 + ks * 32 + koff];
#pragma unroll
      for (int ct = 0; ct < 16; ++ct) {
        s16x8 b = *(const s16x8*)(Wt + (size_t)(ct * 16 + colb) * 256 + ks * 32 + koff);
        acc[ct] = __builtin_amdgcn_mfma_f32_16x16x32_bf16(a, b, acc[ct], 0, 0, 0);
      }
    }
#pragma unroll
    for (int ct = 0; ct < 16; ++ct) {
      int col = ct * 16 + colb;
      float bv = bias[col];
#pragma unroll
      for (int r = 0; r < 4; ++r) {
        long node = m0 + 16 * w + (l >> 4) * 4 + r;   // D: row=(lane>>4)*4+reg, col=lane&15 (verified layout)
        if (node < M) {
          float v = acc[ct][r] + bv;
          if (of) of[node * 256 + col] = v;
          else    o16[node * 256 + col] = (unsigned short)f2b(v);
        }
      }
    }
  }
}

// Pass A: per 64-edge block: edge_attr = [cos(rel*Wt+bt) | msg] (bf16, LDS),
// e = attr @ WeT (MFMA, f32 LDS), alpha = q[dst]·(k[src]+e)/sqrt(C),
// ex = exp(alpha) stored, denom accumulated atomically.
__global__ __launch_bounds__(256) void edge_pass_a(
    const int* __restrict__ ei, const float* __restrict__ tvec,
    const float* __restrict__ lu, const float* __restrict__ msg,
    const float* __restrict__ Wtim, const float* __restrict__ btim,
    const short* __restrict__ WeT,
    const unsigned short* __restrict__ Q16, const unsigned short* __restrict__ K16,
    float* __restrict__ exb, float* __restrict__ denom)
{
  __shared__ __align__(16) char smraw[66560];  // union: attr[64][264] bf16 -> elds[64][260] f32
  short* attr = (short*)smraw;
  float* elds = (float*)smraw;
  __shared__ int srci[64], dsti[64];
  __shared__ float rel[64];

  const int tid = threadIdx.x;
  const int l = tid & 63;
  const int w = tid >> 6;
  const int e0 = blockIdx.x * 64;

  if (tid < 64) {
    int s = ei[e0 + tid];
    int d = ei[E_EDGES + e0 + tid];
    srci[tid] = s; dsti[tid] = d;
    rel[tid] = tvec[e0 + tid] - lu[s];
  }
  __syncthreads();

  if (w < 2) {                       // time-encoder cols 0..127
    int col = w * 64 + l;
    float wt = Wtim[col], bt = btim[col];
#pragma unroll 4
    for (int e = 0; e < 64; ++e)
      attr[e * 264 + col] = f2b(__cosf(rel[e] * wt + bt));
  } else {                           // msg cols 128..255
    int col = (w - 2) * 64 + l;
#pragma unroll 4
    for (int e = 0; e < 64; ++e)
      attr[e * 264 + 128 + col] = f2b(msg[(size_t)(e0 + e) * 128 + col]);
  }
  __syncthreads();

  const int arow = 16 * w + (l & 15);
  const int koff = (l >> 4) * 8;
  const int colb = l & 15;
  f32x4 acc[16];
#pragma unroll
  for (int ct = 0; ct < 16; ++ct) acc[ct] = (f32x4)(0.0f);
#pragma unroll
  for (int ks = 0; ks < 8; ++ks) {
    s16x8 a = *(const s16x8*)&attr[arow * 264 + ks * 32 + koff];
#pragma unroll
    for (int ct = 0; ct < 16; ++ct) {
      s16x8 b = *(const s16x8*)(WeT + (size_t)(ct * 16 + colb) * 256 + ks * 32 + koff);
      acc[ct] = __builtin_amdgcn_mfma_f32_16x16x32_bf16(a, b, acc[ct], 0, 0, 0);
    }
  }
  __syncthreads();  // everyone done reading attr
#pragma unroll
  for (int ct = 0; ct < 16; ++ct)
#pragma unroll
    for (int r = 0; r < 4; ++r)
      elds[(16 * w + (l >> 4) * 4 + r) * 260 + ct * 16 + colb] = acc[ct][r];
  __syncthreads();

  { // alpha: 4 lanes per edge: (head, half) split, shfl-combine halves
    const int e = 16 * w + (l >> 2);
    const int head = (l >> 1) & 1;
    const int half = l & 1;
    const int off = head * 128 + half * 64;
    const int d = dsti[e], s = srci[e];
    const unsigned short* qp = Q16 + (size_t)d * 256 + off;
    const unsigned short* kp = K16 + (size_t)s * 256 + off;
    const float* ep = &elds[e * 260 + off];
    float accd = 0.f;
#pragma unroll
    for (int i = 0; i < 64; i += 8) {
      s16x8 qv = *(const s16x8*)(qp + i);
      s16x8 kv = *(const s16x8*)(kp + i);
#pragma unroll
      for (int j = 0; j < 8; ++j)
        accd += b2f((unsigned short)qv[j]) * (b2f((unsigned short)kv[j]) + ep[i + j]);
    }
    accd += __shfl_xor(accd, 1);
    if (half == 0) {
      float ex = __expf(accd * INV_SQRT_C);   // no max-subtract: |alpha| small, exact math
      exb[(size_t)(e0 + e) * 2 + head] = ex;
      atomicAdd(&denom[(size_t)d * 2 + head], ex);
    }
  }
}

// Pass B: recompute e, then out[dst] += (v[src]+e) * ex/denom  (coalesced atomics)
__global__ __launch_bounds__(256) void edge_pass_b(
    const int* __restrict__ ei, const float* __restrict__ tvec,
    const float* __restrict__ lu, const float* __restrict__ msg,
    const float* __restrict__ Wtim, const float* __restrict__ btim,
    const short* __restrict__ WeT,
    const unsigned short* __restrict__ V16,
    const float* __restrict__ exb, const float* __restrict__ denom,
    float* __restrict__ out)
{
  __shared__ __align__(16) char smraw[66560];
  short* attr = (short*)smraw;
  float* elds = (float*)smraw;
  __shared__ int srci[64], dsti[64];
  __shared__ float rel[64];
  __shared__ float wgt[128];

  const int tid = threadIdx.x;
  const int l = tid & 63;
  const int w = tid >> 6;
  const int e0 = blockIdx.x * 64;

  if (tid < 64) {
    int s = ei[e0 + tid];
    int d = ei[E_EDGES + e0 + tid];
    srci[tid] = s; dsti[tid] = d;
    rel[tid] = tvec[e0 + tid] - lu[s];
    wgt[tid * 2]     = exb[(size_t)(e0 + tid) * 2]     / (denom[(size_t)d * 2]     + 1e-16f);
    wgt[tid * 2 + 1] = exb[(size_t)(e0 + tid) * 2 + 1] / (denom[(size_t)d * 2 + 1] + 1e-16f);
  }
  __syncthreads();

  if (w < 2) {
    int col = w * 64 + l;
    float wt = Wtim[col], bt = btim[col];
#pragma unroll 4
    for (int e = 0; e < 64; ++e)
      attr[e * 264 + col] = f2b(__cosf(rel[e] * wt + bt));
  } else {
    int col = (w - 2) * 64 + l;
#pragma unroll 4
    for (int e = 0; e < 64; ++e)
      attr[e * 264 + 128 + col] = f2b(msg[(size_t)(e0 + e) * 128 + col]);
  }
  __syncthreads();

  const int arow = 16 * w + (l & 15);
  const int koff = (l >> 4) * 8;
  const int colb = l & 15;
  f32x4 acc[16];
#pragma unroll
  for (int ct = 0; ct < 16; ++ct) acc[ct] = (f32x4)(0.0f);
#pragma unroll
  for (int ks = 0; ks < 8; ++ks) {
    s16x8 a = *(const s16x8*)&attr[arow * 264 + ks * 32 + koff];
#pragma unroll
    for (int ct = 0; ct < 16; ++ct) {
      s16x8 b = *(const s16x8*)(WeT + (size_t)(ct * 16 + colb) * 256 + ks * 32 + koff);
      acc[ct] = __builtin_amdgcn_mfma_f32_16x16x32_bf16(a, b, acc[ct], 0, 0, 0);
    }
  }
  __syncthreads();
#pragma unroll
  for (int ct = 0; ct < 16; ++ct)
#pragma unroll
    for (int r = 0; r < 4; ++r)
      elds[(16 * w + (l >> 4) * 4 + r) * 260 + ct * 16 + colb] = acc[ct][r];
  __syncthreads();

  { // scatter: thread = output column, loop edges; atomics coalesced per edge
    const int c = tid;
    const int h = c >> 7;
    const float* ebase = elds + c;
    for (int e = 0; e < 64; ++e) {
      int s = srci[e], d = dsti[e];
      float val = (b2f(V16[(size_t)s * 256 + c]) + ebase[e * 260]) * wgt[e * 2 + h];
      atomicAdd(&out[(size_t)d * 256 + c], val);
    }
  }
}

extern "C" void kernel_launch(void* const* d_in, const int* in_sizes, int n_in,
                              void* d_out, int out_size, void* d_ws, size_t ws_size,
                              hipStream_t stream) {
  const float* x_user  = (const float*)d_in[0];
  const float* x_item  = (const float*)d_in[1];
  const float* lu_user = (const float*)d_in[2];
  const float* lu_item = (const float*)d_in[3];
  const int*   ei_a    = (const int*)d_in[4];
  const int*   ei_b    = (const int*)d_in[5];
  const float* t_a     = (const float*)d_in[6];
  const float* t_b     = (const float*)d_in[7];
  const float* msg_a   = (const float*)d_in[8];
  const float* msg_b   = (const float*)d_in[9];
  const float* W_t     = (const float*)d_in[10];
  const float* b_t     = (const float*)d_in[11];
  const float* Wq_a = (const float*)d_in[12]; const float* bq_a = (const float*)d_in[13];
  const float* Wk_a = (const float*)d_in[14]; const float* bk_a = (const float*)d_in[15];
  const float* Wv_a = (const float*)d_in[16]; const float* bv_a = (const float*)d_in[17];
  const float* We_a = (const float*)d_in[18];
  const float* Ws_a = (const float*)d_in[19]; const float* bs_a = (const float*)d_in[20];
  const float* Wq_b = (const float*)d_in[21]; const float* bq_b = (const float*)d_in[22];
  const float* Wk_b = (const float*)d_in[23]; const float* bk_b = (const float*)d_in[24];
  const float* Wv_b = (const float*)d_in[25]; const float* bv_b = (const float*)d_in[26];
  const float* We_b = (const float*)d_in[27];
  const float* Ws_b = (const float*)d_in[28]; const float* bs_b = (const float*)d_in[29];

  // ws layout
  char* ws = (char*)d_ws;
  size_t off = 0;
  short* WtT = (short*)(ws + off); off += (size_t)10 * 65536 * 2;        // 1.31 MB
  unsigned short* Q16 = (unsigned short*)(ws + off); off += (size_t)N_NODES * 256 * 2;
  unsigned short* K16 = (unsigned short*)(ws + off); off += (size_t)N_NODES * 256 * 2;
  unsigned short* V16 = (unsigned short*)(ws + off); off += (size_t)N_NODES * 256 * 2;
  float* exb   = (float*)(ws + off); off += (size_t)E_EDGES * 2 * 4;
  float* denom = (float*)(ws + off); off += (size_t)N_NODES * 2 * 4;
  if (ws_size < off) return;   // fail loudly (output stays poisoned)

  float* out_user = (float*)d_out;
  float* out_item = (float*)d_out + (size_t)N_NODES * 256;

  WPtrs wp;
  wp.w[0] = Wq_a; wp.w[1] = Wk_a; wp.w[2] = Wv_a; wp.w[3] = Ws_a; wp.w[4] = We_a;
  wp.w[5] = Wq_b; wp.w[6] = Wk_b; wp.w[7] = Wv_b; wp.w[8] = Ws_b; wp.w[9] = We_b;

  dim3 blk(256);
  dim3 gW(10);
  dim3 gN((N_NODES + 63) / 64);
  dim3 gE(E_EDGES / 64);

  prep_transpose<<<gW, blk, 0, stream>>>(wp, WtT);

  // ---- type a: user --to--> item  (dst=item, out_item) ----
  node_gemm<<<gN, blk, 0, stream>>>(x_user, N_NODES,
      WtT + 1 * 65536, bk_a, K16, nullptr,
      WtT + 2 * 65536, bv_a, V16, nullptr);
  node_gemm<<<gN, blk, 0, stream>>>(x_item, N_NODES,
      WtT + 0 * 65536, bq_a, Q16, nullptr,
      WtT + 3 * 65536, bs_a, nullptr, out_item);
  hipMemsetAsync(denom, 0, (size_t)N_NODES * 2 * 4, stream);
  edge_pass_a<<<gE, blk, 0, stream>>>(ei_a, t_a, lu_user, msg_a, W_t, b_t,
      WtT + 4 * 65536, Q16, K16, exb, denom);
  edge_pass_b<<<gE, blk, 0, stream>>>(ei_a, t_a, lu_user, msg_a, W_t, b_t,
      WtT + 4 * 65536, V16, exb, denom, out_item);

  // ---- type b: item --rev_to--> user  (dst=user, out_user) ----
  node_gemm<<<gN, blk, 0, stream>>>(x_item, N_NODES,
      WtT + 6 * 65536, bk_b, K16, nullptr,
      WtT + 7 * 65536, bv_b, V16, nullptr);
  node_gemm<<<gN, blk, 0, stream>>>(x_user, N_NODES,
      WtT + 5 * 65536, bq_b, Q16, nullptr,
      WtT + 8 * 65536, bs_b, nullptr, out_user);
  hipMemsetAsync(denom, 0, (size_t)N_NODES * 2 * 4, stream);
  edge_pass_a<<<gE, blk, 0, stream>>>(ei_b, t_b, lu_item, msg_b, W_t, b_t,
      WtT + 9 * 65536, Q16, K16, exb, denom);
  edge_pass_b<<<gE, blk, 0, stream>>>(ei_b, t_b, lu_item, msg_b, W_t, b_t,
      WtT + 9 * 65536, V16, exb, denom, out_user);
}

// Round 2
// 1740.817 us; speedup vs baseline: 1.1332x; 1.1332x over previous
//
#include <hip/hip_runtime.h>
#include <hip/hip_bf16.h>

#define N_NODES 50000
#define E_EDGES 200000
static constexpr float INV_SQRT_C = 0.08838834764831845f; // 1/sqrt(128)

typedef __attribute__((ext_vector_type(4))) float f32x4;
typedef __attribute__((ext_vector_type(8))) short s16x8;
typedef __attribute__((ext_vector_type(4))) short s16x4;

__device__ __forceinline__ float b2f(unsigned short u) {
  union { unsigned u; float f; } x; x.u = ((unsigned)u) << 16; return x.f;
}
__device__ __forceinline__ short f2b(float f) {
  union { float f; unsigned u; } x; x.f = f;
  unsigned r = x.u + 0x7FFFu + ((x.u >> 16) & 1u);  // RNE
  return (short)(r >> 16);
}

struct WPtrs { const float* w[10]; };

// Transpose + convert 10 [256x256] f32 row-major (k-major) weights to
// bf16 col-major: out[c*256 + k] = W[k][c]
__global__ __launch_bounds__(256) void prep_transpose(WPtrs p, short* __restrict__ out) {
  const float* w = p.w[blockIdx.x];
  short* o = out + (size_t)blockIdx.x * 65536;
  for (int idx = threadIdx.x; idx < 65536; idx += 256) {
    int k = idx >> 8, c = idx & 255;
    o[c * 256 + k] = f2b(w[idx]);
  }
}

// C[M,256] = X[M,256] @ W[256,256] + b for two weight matrices sharing the
// staged X tile. Output either bf16 table (o16) or f32 (of).
__global__ __launch_bounds__(256) void node_gemm(
    const float* __restrict__ X, int M,
    const short* __restrict__ Wt0, const float* __restrict__ bias0,
    unsigned short* __restrict__ o16_0, float* __restrict__ of0,
    const short* __restrict__ Wt1, const float* __restrict__ bias1,
    unsigned short* __restrict__ o16_1, float* __restrict__ of1)
{
  __shared__ short As[64 * 264];
  const int tid = threadIdx.x;
  const int l = tid & 63;
  const int w = tid >> 6;
  const long m0 = (long)blockIdx.x * 64;

  { // stage 64 rows of X -> bf16 LDS
    const int j4 = tid & 63;
    const int rb = tid >> 6;
#pragma unroll
    for (int i = 0; i < 16; ++i) {
      int r = rb + i * 4;
      long node = m0 + r;
      float4 xv = make_float4(0.f, 0.f, 0.f, 0.f);
      if (node < M) xv = *(const float4*)(X + node * 256 + j4 * 4);
      s16x4 sv; sv[0] = f2b(xv.x); sv[1] = f2b(xv.y); sv[2] = f2b(xv.z); sv[3] = f2b(xv.w);
      *(s16x4*)&As[r * 264 + j4 * 4] = sv;
    }
  }
  __syncthreads();

  const int arow = 16 * w + (l & 15);
  const int koff = (l >> 4) * 8;
  const int colb = l & 15;

#pragma unroll 1
  for (int job = 0; job < 2; ++job) {
    const short* Wt = job ? Wt1 : Wt0;
    const float* bias = job ? bias1 : bias0;
    unsigned short* o16 = job ? o16_1 : o16_0;
    float* of = job ? of1 : of0;

    f32x4 acc[16];
#pragma unroll
    for (int ct = 0; ct < 16; ++ct) acc[ct] = (f32x4)(0.0f);
#pragma unroll
    for (int ks = 0; ks < 8; ++ks) {
      s16x8 a = *(const s16x8*)&As[arow * 264 + ks * 32 + koff];
#pragma unroll
      for (int ct = 0; ct < 16; ++ct) {
        s16x8 b = *(const s16x8*)(Wt + (size_t)(ct * 16 + colb) * 256 + ks * 32 + koff);
        acc[ct] = __builtin_amdgcn_mfma_f32_16x16x32_bf16(a, b, acc[ct], 0, 0, 0);
      }
    }
#pragma unroll
    for (int ct = 0; ct < 16; ++ct) {
      int col = ct * 16 + colb;
      float bv = bias[col];
#pragma unroll
      for (int r = 0; r < 4; ++r) {
        long node = m0 + 16 * w + (l >> 4) * 4 + r;
        if (node < M) {
          float v = acc[ct][r] + bv;
          if (of) of[node * 256 + col] = v;
          else    o16[node * 256 + col] = (unsigned short)f2b(v);
        }
      }
    }
  }
}

// ---------------- CSR build ----------------
__global__ __launch_bounds__(256) void csr_count(const int* __restrict__ ei, int* __restrict__ counts) {
  int t = blockIdx.x * 256 + threadIdx.x;
  if (t < E_EDGES) atomicAdd(&counts[ei[E_EDGES + t]], 1);
}

// single-block exclusive scan over n counts -> start[0..n], cursor copy
__global__ __launch_bounds__(1024) void csr_scan(const int* __restrict__ counts,
                                                 int* __restrict__ start,
                                                 int* __restrict__ cursor, int n) {
  __shared__ int wsum[16];
  __shared__ int chunk_tot;
  __shared__ int carry_s;
  const int tid = threadIdx.x, lane = tid & 63, wid = tid >> 6;
  if (tid == 0) carry_s = 0;
  __syncthreads();
  for (int base = 0; base < n; base += 1024) {
    int gi = base + tid;
    int x = (gi < n) ? counts[gi] : 0;
    int v = x;
#pragma unroll
    for (int d = 1; d < 64; d <<= 1) {
      int t = __shfl_up(v, d);
      if (lane >= d) v += t;
    }
    if (lane == 63) wsum[wid] = v;
    __syncthreads();
    if (tid == 0) {
      int run = 0;
#pragma unroll
      for (int i = 0; i < 16; ++i) { int t = wsum[i]; wsum[i] = run; run += t; }
      chunk_tot = run;
    }
    __syncthreads();
    if (gi < n) {
      int excl = carry_s + wsum[wid] + v - x;
      start[gi] = excl;
      cursor[gi] = excl;
    }
    __syncthreads();
    if (tid == 0) carry_s += chunk_tot;
  }
  if (tid == 0) start[n] = carry_s;
}

__global__ __launch_bounds__(256) void csr_fill(const int* __restrict__ ei,
                                                int* __restrict__ cursor,
                                                int* __restrict__ eidx, int* __restrict__ esrc) {
  int t = blockIdx.x * 256 + threadIdx.x;
  if (t < E_EDGES) {
    int d = ei[E_EDGES + t];
    int p = atomicAdd(&cursor[d], 1);
    eidx[p] = t;
    esrc[p] = ei[t];
  }
}

// ---------------- edge compute (pass A, new) ----------------
// per 64-edge block: attr = [cos(rel*Wt+bt) | msg] bf16 in LDS, e = attr @ WeT
// (MFMA) -> bf16 back into same LDS + streamed to e16 global;
// alpha = q[dst]·(k[src]+e)/sqrt(C); ex = exp(alpha) stored. No atomics.
__global__ __launch_bounds__(256) void edge_compute(
    const int* __restrict__ ei, const float* __restrict__ tvec,
    const float* __restrict__ lu, const float* __restrict__ msg,
    const float* __restrict__ Wtim, const float* __restrict__ btim,
    const short* __restrict__ WeT,
    const unsigned short* __restrict__ Q16, const unsigned short* __restrict__ K16,
    unsigned short* __restrict__ e16g, float* __restrict__ exb)
{
  __shared__ short attr[64 * 264];     // bf16: input attr, then overwritten with e
  __shared__ int srci[64], dsti[64];
  __shared__ float rel[64];

  const int tid = threadIdx.x;
  const int l = tid & 63;
  const int w = tid >> 6;
  const int e0 = blockIdx.x * 64;

  if (tid < 64) {
    int s = ei[e0 + tid];
    int d = ei[E_EDGES + e0 + tid];
    srci[tid] = s; dsti[tid] = d;
    rel[tid] = tvec[e0 + tid] - lu[s];
  }
  __syncthreads();

  if (w < 2) {                       // time-encoder cols 0..127
    int col = w * 64 + l;
    float wt = Wtim[col], bt = btim[col];
#pragma unroll 4
    for (int e = 0; e < 64; ++e)
      attr[e * 264 + col] = f2b(__cosf(rel[e] * wt + bt));
  } else {                           // msg cols 128..255
    int col = (w - 2) * 64 + l;
#pragma unroll 4
    for (int e = 0; e < 64; ++e)
      attr[e * 264 + 128 + col] = f2b(msg[(size_t)(e0 + e) * 128 + col]);
  }
  __syncthreads();

  const int arow = 16 * w + (l & 15);
  const int koff = (l >> 4) * 8;
  const int colb = l & 15;
  f32x4 acc[16];
#pragma unroll
  for (int ct = 0; ct < 16; ++ct) acc[ct] = (f32x4)(0.0f);
#pragma unroll
  for (int ks = 0; ks < 8; ++ks) {
    s16x8 a = *(const s16x8*)&attr[arow * 264 + ks * 32 + koff];
#pragma unroll
    for (int ct = 0; ct < 16; ++ct) {
      s16x8 b = *(const s16x8*)(WeT + (size_t)(ct * 16 + colb) * 256 + ks * 32 + koff);
      acc[ct] = __builtin_amdgcn_mfma_f32_16x16x32_bf16(a, b, acc[ct], 0, 0, 0);
    }
  }
  __syncthreads();  // all waves done reading attr
#pragma unroll
  for (int ct = 0; ct < 16; ++ct)
#pragma unroll
    for (int r = 0; r < 4; ++r)
      attr[(16 * w + (l >> 4) * 4 + r) * 264 + ct * 16 + colb] = f2b(acc[ct][r]);
  __syncthreads();

  // stream e (bf16) to global, coalesced
#pragma unroll
  for (int it = 0; it < 8; ++it) {
    int row = (tid >> 5) + it * 8;
    int cg = tid & 31;
    *(s16x8*)(e16g + (size_t)(e0 + row) * 256 + cg * 8) = *(const s16x8*)&attr[row * 264 + cg * 8];
  }

  { // alpha: 4 lanes per edge: (head, half) split, shfl-combine halves
    const int e = 16 * w + (l >> 2);
    const int head = (l >> 1) & 1;
    const int half = l & 1;
    const int off = head * 128 + half * 64;
    const int d = dsti[e], s = srci[e];
    const unsigned short* qp = Q16 + (size_t)d * 256 + off;
    const unsigned short* kp = K16 + (size_t)s * 256 + off;
    const short* ep = &attr[e * 264 + off];
    float accd = 0.f;
#pragma unroll
    for (int i = 0; i < 64; i += 8) {
      s16x8 qv = *(const s16x8*)(qp + i);
      s16x8 kv = *(const s16x8*)(kp + i);
      s16x8 ev = *(const s16x8*)(ep + i);
#pragma unroll
      for (int j = 0; j < 8; ++j)
        accd += b2f((unsigned short)qv[j]) * (b2f((unsigned short)kv[j]) + b2f((unsigned short)ev[j]));
    }
    accd += __shfl_xor(accd, 1);
    if (half == 0)
      exb[(size_t)(e0 + e) * 2 + head] = __expf(accd * INV_SQRT_C);
  }
}

// ---------------- aggregate: one wave per dst node ----------------
__global__ __launch_bounds__(256) void aggregate(
    const int* __restrict__ start, const int* __restrict__ eidx, const int* __restrict__ esrc,
    const float* __restrict__ exb, const unsigned short* __restrict__ e16,
    const unsigned short* __restrict__ V16, float* __restrict__ out)
{
  const int d = blockIdx.x * 4 + (threadIdx.x >> 6);
  if (d >= N_NODES) return;
  const int lane = threadIdx.x & 63;
  const int s0 = start[d], s1 = start[d + 1];
  if (s1 <= s0) return;
  const int h = lane >> 5;            // cols lane*4..+3 all in head (lane>>5)
  float denom = 0.f;
  for (int p = s0; p < s1; ++p) denom += exb[(size_t)eidx[p] * 2 + h];
  denom += 1e-16f;
  float acc0 = 0.f, acc1 = 0.f, acc2 = 0.f, acc3 = 0.f;
  const int c0 = lane * 4;
  for (int p = s0; p < s1; ++p) {
    int e = eidx[p], s = esrc[p];
    float wv = exb[(size_t)e * 2 + h] / denom;
    s16x4 ev = *(const s16x4*)(e16 + (size_t)e * 256 + c0);
    s16x4 vv = *(const s16x4*)(V16 + (size_t)s * 256 + c0);
    acc0 += (b2f((unsigned short)vv[0]) + b2f((unsigned short)ev[0])) * wv;
    acc1 += (b2f((unsigned short)vv[1]) + b2f((unsigned short)ev[1])) * wv;
    acc2 += (b2f((unsigned short)vv[2]) + b2f((unsigned short)ev[2])) * wv;
    acc3 += (b2f((unsigned short)vv[3]) + b2f((unsigned short)ev[3])) * wv;
  }
  float4* op = (float4*)(out + (size_t)d * 256 + c0);
  float4 o = *op;
  o.x += acc0; o.y += acc1; o.z += acc2; o.w += acc3;
  *op = o;
}

// ---------------- fallback (old) path kernels ----------------
__global__ __launch_bounds__(256) void edge_pass_a(
    const int* __restrict__ ei, const float* __restrict__ tvec,
    const float* __restrict__ lu, const float* __restrict__ msg,
    const float* __restrict__ Wtim, const float* __restrict__ btim,
    const short* __restrict__ WeT,
    const unsigned short* __restrict__ Q16, const unsigned short* __restrict__ K16,
    float* __restrict__ exb, float* __restrict__ denom)
{
  __shared__ __align__(16) char smraw[66560];
  short* attr = (short*)smraw;
  float* elds = (float*)smraw;
  __shared__ int srci[64], dsti[64];
  __shared__ float rel[64];

  const int tid = threadIdx.x;
  const int l = tid & 63;
  const int w = tid >> 6;
  const int e0 = blockIdx.x * 64;

  if (tid < 64) {
    int s = ei[e0 + tid];
    int d = ei[E_EDGES + e0 + tid];
    srci[tid] = s; dsti[tid] = d;
    rel[tid] = tvec[e0 + tid] - lu[s];
  }
  __syncthreads();

  if (w < 2) {
    int col = w * 64 + l;
    float wt = Wtim[col], bt = btim[col];
#pragma unroll 4
    for (int e = 0; e < 64; ++e)
      attr[e * 264 + col] = f2b(__cosf(rel[e] * wt + bt));
  } else {
    int col = (w - 2) * 64 + l;
#pragma unroll 4
    for (int e = 0; e < 64; ++e)
      attr[e * 264 + 128 + col] = f2b(msg[(size_t)(e0 + e) * 128 + col]);
  }
  __syncthreads();

  const int arow = 16 * w + (l & 15);
  const int koff = (l >> 4) * 8;
  const int colb = l & 15;
  f32x4 acc[16];
#pragma unroll
  for (int ct = 0; ct < 16; ++ct) acc[ct] = (f32x4)(0.0f);
#pragma unroll
  for (int ks = 0; ks < 8; ++ks) {
    s16x8 a = *(const s16x8*)&attr[arow * 264 + ks * 32 + koff];
#pragma unroll
    for (int ct = 0; ct < 16; ++ct) {
      s16x8 b = *(const s16x8*)(WeT + (size_t)(ct * 16 + colb) * 256 + ks * 32 + koff);
      acc[ct] = __builtin_amdgcn_mfma_f32_16x16x32_bf16(a, b, acc[ct], 0, 0, 0);
    }
  }
  __syncthreads();
#pragma unroll
  for (int ct = 0; ct < 16; ++ct)
#pragma unroll
    for (int r = 0; r < 4; ++r)
      elds[(16 * w + (l >> 4) * 4 + r) * 260 + ct * 16 + colb] = acc[ct][r];
  __syncthreads();

  {
    const int e = 16 * w + (l >> 2);
    const int head = (l >> 1) & 1;
    const int half = l & 1;
    const int off = head * 128 + half * 64;
    const int d = dsti[e], s = srci[e];
    const unsigned short* qp = Q16 + (size_t)d * 256 + off;
    const unsigned short* kp = K16 + (size_t)s * 256 + off;
    const float* ep = &elds[e * 260 + off];
    float accd = 0.f;
#pragma unroll
    for (int i = 0; i < 64; i += 8) {
      s16x8 qv = *(const s16x8*)(qp + i);
      s16x8 kv = *(const s16x8*)(kp + i);
#pragma unroll
      for (int j = 0; j < 8; ++j)
        accd += b2f((unsigned short)qv[j]) * (b2f((unsigned short)kv[j]) + ep[i + j]);
    }
    accd += __shfl_xor(accd, 1);
    if (half == 0) {
      float ex = __expf(accd * INV_SQRT_C);
      exb[(size_t)(e0 + e) * 2 + head] = ex;
      atomicAdd(&denom[(size_t)d * 2 + head], ex);
    }
  }
}

__global__ __launch_bounds__(256) void edge_pass_b(
    const int* __restrict__ ei, const float* __restrict__ tvec,
    const float* __restrict__ lu, const float* __restrict__ msg,
    const float* __restrict__ Wtim, const float* __restrict__ btim,
    const short* __restrict__ WeT,
    const unsigned short* __restrict__ V16,
    const float* __restrict__ exb, const float* __restrict__ denom,
    float* __restrict__ out)
{
  __shared__ __align__(16) char smraw[66560];
  short* attr = (short*)smraw;
  float* elds = (float*)smraw;
  __shared__ int srci[64], dsti[64];
  __shared__ float rel[64];
  __shared__ float wgt[128];

  const int tid = threadIdx.x;
  const int l = tid & 63;
  const int w = tid >> 6;
  const int e0 = blockIdx.x * 64;

  if (tid < 64) {
    int s = ei[e0 + tid];
    int d = ei[E_EDGES + e0 + tid];
    srci[tid] = s; dsti[tid] = d;
    rel[tid] = tvec[e0 + tid] - lu[s];
    wgt[tid * 2]     = exb[(size_t)(e0 + tid) * 2]     / (denom[(size_t)d * 2]     + 1e-16f);
    wgt[tid * 2 + 1] = exb[(size_t)(e0 + tid) * 2 + 1] / (denom[(size_t)d * 2 + 1] + 1e-16f);
  }
  __syncthreads();

  if (w < 2) {
    int col = w * 64 + l;
    float wt = Wtim[col], bt = btim[col];
#pragma unroll 4
    for (int e = 0; e < 64; ++e)
      attr[e * 264 + col] = f2b(__cosf(rel[e] * wt + bt));
  } else {
    int col = (w - 2) * 64 + l;
#pragma unroll 4
    for (int e = 0; e < 64; ++e)
      attr[e * 264 + 128 + col] = f2b(msg[(size_t)(e0 + e) * 128 + col]);
  }
  __syncthreads();

  const int arow = 16 * w + (l & 15);
  const int koff = (l >> 4) * 8;
  const int colb = l & 15;
  f32x4 acc[16];
#pragma unroll
  for (int ct = 0; ct < 16; ++ct) acc[ct] = (f32x4)(0.0f);
#pragma unroll
  for (int ks = 0; ks < 8; ++ks) {
    s16x8 a = *(const s16x8*)&attr[arow * 264 + ks * 32 + koff];
#pragma unroll
    for (int ct = 0; ct < 16; ++ct) {
      s16x8 b = *(const s16x8*)(WeT + (size_t)(ct * 16 + colb) * 256 + ks * 32 + koff);
      acc[ct] = __builtin_amdgcn_mfma_f32_16x16x32_bf16(a, b, acc[ct], 0, 0, 0);
    }
  }
  __syncthreads();
#pragma unroll
  for (int ct = 0; ct < 16; ++ct)
#pragma unroll
    for (int r = 0; r < 4; ++r)
      elds[(16 * w + (l >> 4) * 4 + r) * 260 + ct * 16 + colb] = acc[ct][r];
  __syncthreads();

  {
    const int c = tid;
    const int h = c >> 7;
    const float* ebase = elds + c;
    for (int e = 0; e < 64; ++e) {
      int s = srci[e], d = dsti[e];
      float val = (b2f(V16[(size_t)s * 256 + c]) + ebase[e * 260]) * wgt[e * 2 + h];
      atomicAdd(&out[(size_t)d * 256 + c], val);
    }
  }
}

extern "C" void kernel_launch(void* const* d_in, const int* in_sizes, int n_in,
                              void* d_out, int out_size, void* d_ws, size_t ws_size,
                              hipStream_t stream) {
  const float* x_user  = (const float*)d_in[0];
  const float* x_item  = (const float*)d_in[1];
  const float* lu_user = (const float*)d_in[2];
  const float* lu_item = (const float*)d_in[3];
  const int*   ei_a    = (const int*)d_in[4];
  const int*   ei_b    = (const int*)d_in[5];
  const float* t_a     = (const float*)d_in[6];
  const float* t_b     = (const float*)d_in[7];
  const float* msg_a   = (const float*)d_in[8];
  const float* msg_b   = (const float*)d_in[9];
  const float* W_t     = (const float*)d_in[10];
  const float* b_t     = (const float*)d_in[11];
  const float* Wq_a = (const float*)d_in[12]; const float* bq_a = (const float*)d_in[13];
  const float* Wk_a = (const float*)d_in[14]; const float* bk_a = (const float*)d_in[15];
  const float* Wv_a = (const float*)d_in[16]; const float* bv_a = (const float*)d_in[17];
  const float* We_a = (const float*)d_in[18];
  const float* Ws_a = (const float*)d_in[19]; const float* bs_a = (const float*)d_in[20];
  const float* Wq_b = (const float*)d_in[21]; const float* bq_b = (const float*)d_in[22];
  const float* Wk_b = (const float*)d_in[23]; const float* bk_b = (const float*)d_in[24];
  const float* Wv_b = (const float*)d_in[25]; const float* bv_b = (const float*)d_in[26];
  const float* We_b = (const float*)d_in[27];
  const float* Ws_b = (const float*)d_in[28]; const float* bs_b = (const float*)d_in[29];

  float* out_user = (float*)d_out;
  float* out_item = (float*)d_out + (size_t)N_NODES * 256;

  WPtrs wp;
  wp.w[0] = Wq_a; wp.w[1] = Wk_a; wp.w[2] = Wv_a; wp.w[3] = Ws_a; wp.w[4] = We_a;
  wp.w[5] = Wq_b; wp.w[6] = Wk_b; wp.w[7] = Wv_b; wp.w[8] = Ws_b; wp.w[9] = We_b;

  dim3 blk(256);
  dim3 gW(10);
  dim3 gN((N_NODES + 63) / 64);
  dim3 gE(E_EDGES / 64);
  dim3 gEt((E_EDGES + 255) / 256);
  dim3 gAgg((N_NODES + 3) / 4);

  // ws layout (new path): 184.4 MB
  char* ws = (char*)d_ws;
  size_t off = 0;
  short* WtT = (short*)(ws + off); off += (size_t)10 * 65536 * 2;
  unsigned short* Q16 = (unsigned short*)(ws + off); off += (size_t)N_NODES * 256 * 2;
  unsigned short* K16 = (unsigned short*)(ws + off); off += (size_t)N_NODES * 256 * 2;
  unsigned short* V16 = (unsigned short*)(ws + off); off += (size_t)N_NODES * 256 * 2;
  float* exb   = (float*)(ws + off); off += (size_t)E_EDGES * 2 * 4;
  unsigned short* e16 = (unsigned short*)(ws + off); size_t off_e16 = off; off += (size_t)E_EDGES * 256 * 2;
  int* counts = (int*)(ws + off); off += (size_t)N_NODES * 4;
  int* startb = (int*)(ws + off); off += (size_t)(N_NODES + 4) * 4;
  int* cursor = (int*)(ws + off); off += (size_t)N_NODES * 4;
  int* eidx   = (int*)(ws + off); off += (size_t)E_EDGES * 4;
  int* esrc   = (int*)(ws + off); off += (size_t)E_EDGES * 4;
  const bool new_path = (ws_size >= off);
  // fallback layout reuse: denom where e16 would start
  float* denom = (float*)(ws + off_e16);
  if (!new_path && ws_size < off_e16 + (size_t)N_NODES * 2 * 4) return;

  prep_transpose<<<gW, blk, 0, stream>>>(wp, WtT);

  if (new_path) {
    // ---- type a: user --to--> item ----
    node_gemm<<<gN, blk, 0, stream>>>(x_user, N_NODES,
        WtT + 1 * 65536, bk_a, K16, nullptr, WtT + 2 * 65536, bv_a, V16, nullptr);
    node_gemm<<<gN, blk, 0, stream>>>(x_item, N_NODES,
        WtT + 0 * 65536, bq_a, Q16, nullptr, WtT + 3 * 65536, bs_a, nullptr, out_item);
    hipMemsetAsync(counts, 0, (size_t)N_NODES * 4, stream);
    csr_count<<<gEt, blk, 0, stream>>>(ei_a, counts);
    csr_scan<<<1, 1024, 0, stream>>>(counts, startb, cursor, N_NODES);
    csr_fill<<<gEt, blk, 0, stream>>>(ei_a, cursor, eidx, esrc);
    edge_compute<<<gE, blk, 0, stream>>>(ei_a, t_a, lu_user, msg_a, W_t, b_t,
        WtT + 4 * 65536, Q16, K16, e16, exb);
    aggregate<<<gAgg, blk, 0, stream>>>(startb, eidx, esrc, exb, e16, V16, out_item);

    // ---- type b: item --rev_to--> user ----
    node_gemm<<<gN, blk, 0, stream>>>(x_item, N_NODES,
        WtT + 6 * 65536, bk_b, K16, nullptr, WtT + 7 * 65536, bv_b, V16, nullptr);
    node_gemm<<<gN, blk, 0, stream>>>(x_user, N_NODES,
        WtT + 5 * 65536, bq_b, Q16, nullptr, WtT + 8 * 65536, bs_b, nullptr, out_user);
    hipMemsetAsync(counts, 0, (size_t)N_NODES * 4, stream);
    csr_count<<<gEt, blk, 0, stream>>>(ei_b, counts);
    csr_scan<<<1, 1024, 0, stream>>>(counts, startb, cursor, N_NODES);
    csr_fill<<<gEt, blk, 0, stream>>>(ei_b, cursor, eidx, esrc);
    edge_compute<<<gE, blk, 0, stream>>>(ei_b, t_b, lu_item, msg_b, W_t, b_t,
        WtT + 9 * 65536, Q16, K16, e16, exb);
    aggregate<<<gAgg, blk, 0, stream>>>(startb, eidx, esrc, exb, e16, V16, out_user);
  } else {
    // ---- fallback: round-1 path ----
    node_gemm<<<gN, blk, 0, stream>>>(x_user, N_NODES,
        WtT + 1 * 65536, bk_a, K16, nullptr, WtT + 2 * 65536, bv_a, V16, nullptr);
    node_gemm<<<gN, blk, 0, stream>>>(x_item, N_NODES,
        WtT + 0 * 65536, bq_a, Q16, nullptr, WtT + 3 * 65536, bs_a, nullptr, out_item);
    hipMemsetAsync(denom, 0, (size_t)N_NODES * 2 * 4, stream);
    edge_pass_a<<<gE, blk, 0, stream>>>(ei_a, t_a, lu_user, msg_a, W_t, b_t,
        WtT + 4 * 65536, Q16, K16, exb, denom);
    edge_pass_b<<<gE, blk, 0, stream>>>(ei_a, t_a, lu_user, msg_a, W_t, b_t,
        WtT + 4 * 65536, V16, exb, denom, out_item);
    node_gemm<<<gN, blk, 0, stream>>>(x_item, N_NODES,
        WtT + 6 * 65536, bk_b, K16, nullptr, WtT + 7 * 65536, bv_b, V16, nullptr);
    node_gemm<<<gN, blk, 0, stream>>>(x_user, N_NODES,
        WtT + 5 * 65536, bq_b, Q16, nullptr, WtT + 8 * 65536, bs_b, nullptr, out_user);
    hipMemsetAsync(denom, 0, (size_t)N_NODES * 2 * 4, stream);
    edge_pass_a<<<gE, blk, 0, stream>>>(ei_b, t_b, lu_item, msg_b, W_t, b_t,
        WtT + 9 * 65536, Q16, K16, exb, denom);
    edge_pass_b<<<gE, blk, 0, stream>>>(ei_b, t_b, lu_item, msg_b, W_t, b_t,
        WtT + 9 * 65536, V16, exb, denom, out_user);
  }
}

// Round 3
// 1525.486 us; speedup vs baseline: 1.2932x; 1.1412x over previous
//
#include <hip/hip_runtime.h>
#include <hip/hip_bf16.h>

#define N_NODES 50000
#define E_EDGES 200000
static constexpr float INV_SQRT_C = 0.08838834764831845f; // 1/sqrt(128)

typedef __attribute__((ext_vector_type(4))) float f32x4;
typedef __attribute__((ext_vector_type(8))) short s16x8;
typedef __attribute__((ext_vector_type(4))) short s16x4;

__device__ __forceinline__ float b2f(unsigned short u) {
  union { unsigned u; float f; } x; x.u = ((unsigned)u) << 16; return x.f;
}
__device__ __forceinline__ short f2b(float f) {
  union { float f; unsigned u; } x; x.f = f;
  unsigned r = x.u + 0x7FFFu + ((x.u >> 16) & 1u);  // RNE
  return (short)(r >> 16);
}

struct WPtrs { const float* w[10]; };

// Transpose + convert 10 [256x256] f32 row-major weights to bf16 col-major:
// out[c*256 + k] = W[k][c]
__global__ __launch_bounds__(256) void prep_transpose(WPtrs p, short* __restrict__ out) {
  const float* w = p.w[blockIdx.x];
  short* o = out + (size_t)blockIdx.x * 65536;
  for (int idx = threadIdx.x; idx < 65536; idx += 256) {
    int k = idx >> 8, c = idx & 255;
    o[c * 256 + k] = f2b(w[idx]);
  }
}

// C[M,256] = X[M,256] @ W[256,256] + b for two weight matrices sharing the
// staged X tile. Output either bf16 table (o16) or f32 (of).
__global__ __launch_bounds__(256) void node_gemm(
    const float* __restrict__ X, int M,
    const short* __restrict__ Wt0, const float* __restrict__ bias0,
    unsigned short* __restrict__ o16_0, float* __restrict__ of0,
    const short* __restrict__ Wt1, const float* __restrict__ bias1,
    unsigned short* __restrict__ o16_1, float* __restrict__ of1)
{
  __shared__ short As[64 * 264];
  const int tid = threadIdx.x;
  const int l = tid & 63;
  const int w = tid >> 6;
  const long m0 = (long)blockIdx.x * 64;

  { // stage 64 rows of X -> bf16 LDS
    const int j4 = tid & 63;
    const int rb = tid >> 6;
#pragma unroll
    for (int i = 0; i < 16; ++i) {
      int r = rb + i * 4;
      long node = m0 + r;
      float4 xv = make_float4(0.f, 0.f, 0.f, 0.f);
      if (node < M) xv = *(const float4*)(X + node * 256 + j4 * 4);
      s16x4 sv; sv[0] = f2b(xv.x); sv[1] = f2b(xv.y); sv[2] = f2b(xv.z); sv[3] = f2b(xv.w);
      *(s16x4*)&As[r * 264 + j4 * 4] = sv;
    }
  }
  __syncthreads();

  const int arow = 16 * w + (l & 15);
  const int koff = (l >> 4) * 8;
  const int colb = l & 15;

#pragma unroll 1
  for (int job = 0; job < 2; ++job) {
    const short* Wt = job ? Wt1 : Wt0;
    const float* bias = job ? bias1 : bias0;
    unsigned short* o16 = job ? o16_1 : o16_0;
    float* of = job ? of1 : of0;

    f32x4 acc[16];
#pragma unroll
    for (int ct = 0; ct < 16; ++ct) acc[ct] = (f32x4)(0.0f);
#pragma unroll
    for (int ks = 0; ks < 8; ++ks) {
      s16x8 a = *(const s16x8*)&As[arow * 264 + ks * 32 + koff];
#pragma unroll
      for (int ct = 0; ct < 16; ++ct) {
        s16x8 b = *(const s16x8*)(Wt + (size_t)(ct * 16 + colb) * 256 + ks * 32 + koff);
        acc[ct] = __builtin_amdgcn_mfma_f32_16x16x32_bf16(a, b, acc[ct], 0, 0, 0);
      }
    }
#pragma unroll
    for (int ct = 0; ct < 16; ++ct) {
      int col = ct * 16 + colb;
      float bv = bias[col];
#pragma unroll
      for (int r = 0; r < 4; ++r) {
        long node = m0 + 16 * w + (l >> 4) * 4 + r;
        if (node < M) {
          float v = acc[ct][r] + bv;
          if (of) of[node * 256 + col] = v;
          else    o16[node * 256 + col] = (unsigned short)f2b(v);
        }
      }
    }
  }
}

// ---------------- CSR build ----------------
__global__ __launch_bounds__(256) void csr_count(const int* __restrict__ ei, int* __restrict__ counts) {
  int t = blockIdx.x * 256 + threadIdx.x;
  if (t < E_EDGES) atomicAdd(&counts[ei[E_EDGES + t]], 1);
}

__global__ __launch_bounds__(1024) void csr_scan(const int* __restrict__ counts,
                                                 int* __restrict__ start,
                                                 int* __restrict__ cursor, int n) {
  __shared__ int wsum[16];
  __shared__ int chunk_tot;
  __shared__ int carry_s;
  const int tid = threadIdx.x, lane = tid & 63, wid = tid >> 6;
  if (tid == 0) carry_s = 0;
  __syncthreads();
  for (int base = 0; base < n; base += 1024) {
    int gi = base + tid;
    int x = (gi < n) ? counts[gi] : 0;
    int v = x;
#pragma unroll
    for (int d = 1; d < 64; d <<= 1) {
      int t = __shfl_up(v, d);
      if (lane >= d) v += t;
    }
    if (lane == 63) wsum[wid] = v;
    __syncthreads();
    if (tid == 0) {
      int run = 0;
#pragma unroll
      for (int i = 0; i < 16; ++i) { int t = wsum[i]; wsum[i] = run; run += t; }
      chunk_tot = run;
    }
    __syncthreads();
    if (gi < n) {
      int excl = carry_s + wsum[wid] + v - x;
      start[gi] = excl;
      cursor[gi] = excl;
    }
    __syncthreads();
    if (tid == 0) carry_s += chunk_tot;
  }
  if (tid == 0) start[n] = carry_s;
}

__global__ __launch_bounds__(256) void csr_fill(const int* __restrict__ ei,
                                                int* __restrict__ cursor,
                                                int* __restrict__ eidx, int* __restrict__ esrc) {
  int t = blockIdx.x * 256 + threadIdx.x;
  if (t < E_EDGES) {
    int d = ei[E_EDGES + t];
    int p = atomicAdd(&cursor[d], 1);
    eidx[p] = t;
    esrc[p] = ei[t];
  }
}

// ---------------- edge GEMM: e16 = [cos(rel*Wt+bt) | msg] @ We ----------------
// Pure GEMM, no gathers. 64 edges per block.
__global__ __launch_bounds__(256) void edge_gemm(
    const int* __restrict__ ei, const float* __restrict__ tvec,
    const float* __restrict__ lu, const float* __restrict__ msg,
    const float* __restrict__ Wtim, const float* __restrict__ btim,
    const short* __restrict__ WeT, unsigned short* __restrict__ e16g)
{
  __shared__ short attr[64 * 264];     // bf16 attr, later overwritten with e
  __shared__ float rel[64];

  const int tid = threadIdx.x;
  const int l = tid & 63;
  const int w = tid >> 6;
  const int e0 = blockIdx.x * 64;

  if (tid < 64) rel[tid] = tvec[e0 + tid] - lu[ei[e0 + tid]];
  __syncthreads();

  // msg staging: 64 rows x 32 float4 = 2048 loads over 256 threads (vectorized)
#pragma unroll
  for (int i = 0; i < 8; ++i) {
    int flat = tid + i * 256;
    int row = flat >> 5, c4 = flat & 31;
    float4 mv = *(const float4*)(msg + (size_t)(e0 + row) * 128 + c4 * 4);
    s16x4 sv; sv[0] = f2b(mv.x); sv[1] = f2b(mv.y); sv[2] = f2b(mv.z); sv[3] = f2b(mv.w);
    *(s16x4*)&attr[row * 264 + 128 + c4 * 4] = sv;
  }
  // time-encoder staging: fixed col per thread, 32 rows each (balanced)
  {
    int col = tid & 127;
    int r0 = (tid >> 7) * 32;
    float wt = Wtim[col], bt = btim[col];
#pragma unroll
    for (int i = 0; i < 32; ++i)
      attr[(r0 + i) * 264 + col] = f2b(__cosf(rel[r0 + i] * wt + bt));
  }
  __syncthreads();

  const int arow = 16 * w + (l & 15);
  const int koff = (l >> 4) * 8;
  const int colb = l & 15;
  f32x4 acc[16];
#pragma unroll
  for (int ct = 0; ct < 16; ++ct) acc[ct] = (f32x4)(0.0f);
#pragma unroll
  for (int ks = 0; ks < 8; ++ks) {
    s16x8 a = *(const s16x8*)&attr[arow * 264 + ks * 32 + koff];
#pragma unroll
    for (int ct = 0; ct < 16; ++ct) {
      s16x8 b = *(const s16x8*)(WeT + (size_t)(ct * 16 + colb) * 256 + ks * 32 + koff);
      acc[ct] = __builtin_amdgcn_mfma_f32_16x16x32_bf16(a, b, acc[ct], 0, 0, 0);
    }
  }
  __syncthreads();  // all waves done reading attr
#pragma unroll
  for (int ct = 0; ct < 16; ++ct)
#pragma unroll
    for (int r = 0; r < 4; ++r)
      attr[(16 * w + (l >> 4) * 4 + r) * 264 + ct * 16 + colb] = f2b(acc[ct][r]);
  __syncthreads();

  // stream e (bf16) to global, coalesced 16B stores
#pragma unroll
  for (int it = 0; it < 8; ++it) {
    int row = (tid >> 5) + it * 8;
    int cg = tid & 31;
    *(s16x8*)(e16g + (size_t)(e0 + row) * 256 + cg * 8) = *(const s16x8*)&attr[row * 264 + cg * 8];
  }
}

// ---------------- fused aggregate: one wave per dst node ----------------
// Single pass: out[d] += (Σ_p ex_p·(v+e)) / (Σ_p ex_p + 1e-16)
__global__ __launch_bounds__(256) void aggregate_fused(
    const int* __restrict__ start, const int* __restrict__ eidx, const int* __restrict__ esrc,
    const unsigned short* __restrict__ Q16, const unsigned short* __restrict__ K16,
    const unsigned short* __restrict__ V16, const unsigned short* __restrict__ e16,
    float* __restrict__ out)
{
  const int d = blockIdx.x * 4 + (threadIdx.x >> 6);
  if (d >= N_NODES) return;
  const int lane = threadIdx.x & 63;
  const int s0 = start[d], s1 = start[d + 1];
  if (s1 <= s0) return;
  const int c0 = lane * 4;          // lanes 0-31: head 0 (cols 0-127); 32-63: head 1

  s16x4 qv = *(const s16x4*)(Q16 + (size_t)d * 256 + c0);
  const float q0 = b2f((unsigned short)qv[0]), q1 = b2f((unsigned short)qv[1]);
  const float q2 = b2f((unsigned short)qv[2]), q3 = b2f((unsigned short)qv[3]);

  float den = 0.f;
  float acc0 = 0.f, acc1 = 0.f, acc2 = 0.f, acc3 = 0.f;
  for (int p = s0; p < s1; ++p) {
    int e = eidx[p], s = esrc[p];
    s16x4 ev = *(const s16x4*)(e16 + (size_t)e * 256 + c0);
    s16x4 kv = *(const s16x4*)(K16 + (size_t)s * 256 + c0);
    s16x4 vv = *(const s16x4*)(V16 + (size_t)s * 256 + c0);
    float e0f = b2f((unsigned short)ev[0]), e1f = b2f((unsigned short)ev[1]);
    float e2f = b2f((unsigned short)ev[2]), e3f = b2f((unsigned short)ev[3]);
    float part = q0 * (b2f((unsigned short)kv[0]) + e0f)
               + q1 * (b2f((unsigned short)kv[1]) + e1f)
               + q2 * (b2f((unsigned short)kv[2]) + e2f)
               + q3 * (b2f((unsigned short)kv[3]) + e3f);
    part += __shfl_xor(part, 1);
    part += __shfl_xor(part, 2);
    part += __shfl_xor(part, 4);
    part += __shfl_xor(part, 8);
    part += __shfl_xor(part, 16);    // per-head (32-lane) total
    float ex = __expf(part * INV_SQRT_C);
    den += ex;
    acc0 += ex * (b2f((unsigned short)vv[0]) + e0f);
    acc1 += ex * (b2f((unsigned short)vv[1]) + e1f);
    acc2 += ex * (b2f((unsigned short)vv[2]) + e2f);
    acc3 += ex * (b2f((unsigned short)vv[3]) + e3f);
  }
  float inv = 1.f / (den + 1e-16f);
  float4* op = (float4*)(out + (size_t)d * 256 + c0);
  float4 o = *op;
  o.x += acc0 * inv; o.y += acc1 * inv; o.z += acc2 * inv; o.w += acc3 * inv;
  *op = o;
}

extern "C" void kernel_launch(void* const* d_in, const int* in_sizes, int n_in,
                              void* d_out, int out_size, void* d_ws, size_t ws_size,
                              hipStream_t stream) {
  const float* x_user  = (const float*)d_in[0];
  const float* x_item  = (const float*)d_in[1];
  const float* lu_user = (const float*)d_in[2];
  const float* lu_item = (const float*)d_in[3];
  const int*   ei_a    = (const int*)d_in[4];
  const int*   ei_b    = (const int*)d_in[5];
  const float* t_a     = (const float*)d_in[6];
  const float* t_b     = (const float*)d_in[7];
  const float* msg_a   = (const float*)d_in[8];
  const float* msg_b   = (const float*)d_in[9];
  const float* W_t     = (const float*)d_in[10];
  const float* b_t     = (const float*)d_in[11];
  const float* Wq_a = (const float*)d_in[12]; const float* bq_a = (const float*)d_in[13];
  const float* Wk_a = (const float*)d_in[14]; const float* bk_a = (const float*)d_in[15];
  const float* Wv_a = (const float*)d_in[16]; const float* bv_a = (const float*)d_in[17];
  const float* We_a = (const float*)d_in[18];
  const float* Ws_a = (const float*)d_in[19]; const float* bs_a = (const float*)d_in[20];
  const float* Wq_b = (const float*)d_in[21]; const float* bq_b = (const float*)d_in[22];
  const float* Wk_b = (const float*)d_in[23]; const float* bk_b = (const float*)d_in[24];
  const float* Wv_b = (const float*)d_in[25]; const float* bv_b = (const float*)d_in[26];
  const float* We_b = (const float*)d_in[27];
  const float* Ws_b = (const float*)d_in[28]; const float* bs_b = (const float*)d_in[29];

  float* out_user = (float*)d_out;
  float* out_item = (float*)d_out + (size_t)N_NODES * 256;

  WPtrs wp;
  wp.w[0] = Wq_a; wp.w[1] = Wk_a; wp.w[2] = Wv_a; wp.w[3] = Ws_a; wp.w[4] = We_a;
  wp.w[5] = Wq_b; wp.w[6] = Wk_b; wp.w[7] = Wv_b; wp.w[8] = Ws_b; wp.w[9] = We_b;

  dim3 blk(256);
  dim3 gW(10);
  dim3 gN((N_NODES + 63) / 64);
  dim3 gE(E_EDGES / 64);
  dim3 gEt((E_EDGES + 255) / 256);
  dim3 gAgg((N_NODES + 3) / 4);

  // ws layout: ~183 MB
  char* ws = (char*)d_ws;
  size_t off = 0;
  short* WtT = (short*)(ws + off); off += (size_t)10 * 65536 * 2;
  unsigned short* Q16 = (unsigned short*)(ws + off); off += (size_t)N_NODES * 256 * 2;
  unsigned short* K16 = (unsigned short*)(ws + off); off += (size_t)N_NODES * 256 * 2;
  unsigned short* V16 = (unsigned short*)(ws + off); off += (size_t)N_NODES * 256 * 2;
  unsigned short* e16 = (unsigned short*)(ws + off); off += (size_t)E_EDGES * 256 * 2;
  int* counts = (int*)(ws + off); off += (size_t)N_NODES * 4;
  int* startb = (int*)(ws + off); off += (size_t)(N_NODES + 4) * 4;
  int* cursor = (int*)(ws + off); off += (size_t)N_NODES * 4;
  int* eidx   = (int*)(ws + off); off += (size_t)E_EDGES * 4;
  int* esrc   = (int*)(ws + off); off += (size_t)E_EDGES * 4;
  if (ws_size < off) return;   // fail loudly (output stays poisoned)

  prep_transpose<<<gW, blk, 0, stream>>>(wp, WtT);

  // ---- type a: user --to--> item (dst=item) ----
  node_gemm<<<gN, blk, 0, stream>>>(x_user, N_NODES,
      WtT + 1 * 65536, bk_a, K16, nullptr, WtT + 2 * 65536, bv_a, V16, nullptr);
  node_gemm<<<gN, blk, 0, stream>>>(x_item, N_NODES,
      WtT + 0 * 65536, bq_a, Q16, nullptr, WtT + 3 * 65536, bs_a, nullptr, out_item);
  hipMemsetAsync(counts, 0, (size_t)N_NODES * 4, stream);
  csr_count<<<gEt, blk, 0, stream>>>(ei_a, counts);
  csr_scan<<<1, 1024, 0, stream>>>(counts, startb, cursor, N_NODES);
  csr_fill<<<gEt, blk, 0, stream>>>(ei_a, cursor, eidx, esrc);
  edge_gemm<<<gE, blk, 0, stream>>>(ei_a, t_a, lu_user, msg_a, W_t, b_t,
      WtT + 4 * 65536, e16);
  aggregate_fused<<<gAgg, blk, 0, stream>>>(startb, eidx, esrc, Q16, K16, V16, e16, out_item);

  // ---- type b: item --rev_to--> user (dst=user) ----
  node_gemm<<<gN, blk, 0, stream>>>(x_item, N_NODES,
      WtT + 6 * 65536, bk_b, K16, nullptr, WtT + 7 * 65536, bv_b, V16, nullptr);
  node_gemm<<<gN, blk, 0, stream>>>(x_user, N_NODES,
      WtT + 5 * 65536, bq_b, Q16, nullptr, WtT + 8 * 65536, bs_b, nullptr, out_user);
  hipMemsetAsync(counts, 0, (size_t)N_NODES * 4, stream);
  csr_count<<<gEt, blk, 0, stream>>>(ei_b, counts);
  csr_scan<<<1, 1024, 0, stream>>>(counts, startb, cursor, N_NODES);
  csr_fill<<<gEt, blk, 0, stream>>>(ei_b, cursor, eidx, esrc);
  edge_gemm<<<gE, blk, 0, stream>>>(ei_b, t_b, lu_item, msg_b, W_t, b_t,
      WtT + 9 * 65536, e16);
  aggregate_fused<<<gAgg, blk, 0, stream>>>(startb, eidx, esrc, Q16, K16, V16, e16, out_user);
}

// Round 4
// 791.967 us; speedup vs baseline: 2.4910x; 1.9262x over previous
//
#include <hip/hip_runtime.h>
#include <hip/hip_bf16.h>

#define N_NODES 50000
#define E_EDGES 200000
static constexpr float INV_SQRT_C = 0.08838834764831845f; // 1/sqrt(128)

typedef __attribute__((ext_vector_type(4))) float f32x4;
typedef __attribute__((ext_vector_type(8))) short s16x8;
typedef __attribute__((ext_vector_type(4))) short s16x4;

__device__ __forceinline__ float b2f(unsigned short u) {
  union { unsigned u; float f; } x; x.u = ((unsigned)u) << 16; return x.f;
}
__device__ __forceinline__ short f2b(float f) {
  union { float f; unsigned u; } x; x.f = f;
  unsigned r = x.u + 0x7FFFu + ((x.u >> 16) & 1u);  // RNE
  return (short)(r >> 16);
}

struct WPtrs { const float* w[10]; };

// Transpose + convert 10 [256x256] f32 weights to bf16 col-major.
// 8 blocks per weight (80 total) for parallelism.
__global__ __launch_bounds__(256) void prep_transpose(WPtrs p, short* __restrict__ out) {
  const int wi = blockIdx.x >> 3, seg = blockIdx.x & 7;
  const float* w = p.w[wi];
  short* o = out + (size_t)wi * 65536;
  for (int idx = seg * 8192 + threadIdx.x; idx < (seg + 1) * 8192; idx += 256) {
    int k = idx >> 8, c = idx & 255;
    o[c * 256 + k] = f2b(w[idx]);
  }
}

// ---------------- node GEMM (register-efficient re-tile) ----------------
// 512 threads = 8 waves; wave w owns cols [32w,32w+32) (2 ct tiles);
// ks-outer loop: 2 B-loads feed 8 MFMAs (4 row-tiles x 2 ct).
// Two weight jobs share one staged X tile.
__global__ __launch_bounds__(512) void node_gemm2(
    const float* __restrict__ X, int M,
    const short* __restrict__ Wt0, const float* __restrict__ bias0,
    unsigned short* __restrict__ o16_0, float* __restrict__ of0,
    const short* __restrict__ Wt1, const float* __restrict__ bias1,
    unsigned short* __restrict__ o16_1, float* __restrict__ of1)
{
  __shared__ short As[64 * 264];
  const int tid = threadIdx.x;
  const int l = tid & 63;
  const int w = tid >> 6;
  const long m0 = (long)blockIdx.x * 64;

  // stage 64 rows of X -> bf16 LDS (vectorized, coalesced)
#pragma unroll
  for (int i = 0; i < 8; ++i) {
    int flat = tid + i * 512;
    int r = flat >> 6, c4 = flat & 63;
    long node = m0 + r;
    float4 xv = make_float4(0.f, 0.f, 0.f, 0.f);
    if (node < M) xv = *(const float4*)(X + node * 256 + c4 * 4);
    s16x4 sv; sv[0] = f2b(xv.x); sv[1] = f2b(xv.y); sv[2] = f2b(xv.z); sv[3] = f2b(xv.w);
    *(s16x4*)&As[r * 264 + c4 * 4] = sv;
  }
  __syncthreads();

  const int colb = l & 15;
  const int koff = (l >> 4) * 8;

#pragma unroll 1
  for (int job = 0; job < 2; ++job) {
    const short* Wt = job ? Wt1 : Wt0;
    const float* bias = job ? bias1 : bias0;
    unsigned short* o16 = job ? o16_1 : o16_0;
    float* of = job ? of1 : of0;

    f32x4 acc[4][2];
#pragma unroll
    for (int m = 0; m < 4; ++m) { acc[m][0] = (f32x4)(0.0f); acc[m][1] = (f32x4)(0.0f); }

#pragma unroll
    for (int ks = 0; ks < 8; ++ks) {
      s16x8 b0 = *(const s16x8*)(Wt + (size_t)((2 * w + 0) * 16 + colb) * 256 + ks * 32 + koff);
      s16x8 b1 = *(const s16x8*)(Wt + (size_t)((2 * w + 1) * 16 + colb) * 256 + ks * 32 + koff);
#pragma unroll
      for (int m = 0; m < 4; ++m) {
        s16x8 a = *(const s16x8*)&As[(16 * m + (l & 15)) * 264 + ks * 32 + koff];
        acc[m][0] = __builtin_amdgcn_mfma_f32_16x16x32_bf16(a, b0, acc[m][0], 0, 0, 0);
        acc[m][1] = __builtin_amdgcn_mfma_f32_16x16x32_bf16(a, b1, acc[m][1], 0, 0, 0);
      }
    }
#pragma unroll
    for (int j = 0; j < 2; ++j) {
      int col = (2 * w + j) * 16 + colb;
      float bv = bias[col];
#pragma unroll
      for (int m = 0; m < 4; ++m)
#pragma unroll
        for (int r = 0; r < 4; ++r) {
          long node = m0 + 16 * m + (l >> 4) * 4 + r;
          if (node < M) {
            float v = acc[m][j][r] + bv;
            if (of) of[node * 256 + col] = v;
            else    o16[node * 256 + col] = (unsigned short)f2b(v);
          }
        }
    }
  }
}

// ---------------- CSR build ----------------
__global__ __launch_bounds__(256) void csr_count(const int* __restrict__ ei, int* __restrict__ counts) {
  int t = blockIdx.x * 256 + threadIdx.x;
  if (t < E_EDGES) atomicAdd(&counts[ei[E_EDGES + t]], 1);
}

__global__ __launch_bounds__(1024) void csr_scan(const int* __restrict__ counts,
                                                 int* __restrict__ start,
                                                 int* __restrict__ cursor, int n) {
  __shared__ int wsum[16];
  __shared__ int chunk_tot;
  __shared__ int carry_s;
  const int tid = threadIdx.x, lane = tid & 63, wid = tid >> 6;
  if (tid == 0) carry_s = 0;
  __syncthreads();
  for (int base = 0; base < n; base += 1024) {
    int gi = base + tid;
    int x = (gi < n) ? counts[gi] : 0;
    int v = x;
#pragma unroll
    for (int d = 1; d < 64; d <<= 1) {
      int t = __shfl_up(v, d);
      if (lane >= d) v += t;
    }
    if (lane == 63) wsum[wid] = v;
    __syncthreads();
    if (tid == 0) {
      int run = 0;
#pragma unroll
      for (int i = 0; i < 16; ++i) { int t = wsum[i]; wsum[i] = run; run += t; }
      chunk_tot = run;
    }
    __syncthreads();
    if (gi < n) {
      int excl = carry_s + wsum[wid] + v - x;
      start[gi] = excl;
      cursor[gi] = excl;
    }
    __syncthreads();
    if (tid == 0) carry_s += chunk_tot;
  }
  if (tid == 0) start[n] = carry_s;
}

__global__ __launch_bounds__(256) void csr_fill(const int* __restrict__ ei,
                                                int* __restrict__ cursor,
                                                int* __restrict__ eidx, int* __restrict__ esrc) {
  int t = blockIdx.x * 256 + threadIdx.x;
  if (t < E_EDGES) {
    int d = ei[E_EDGES + t];
    int p = atomicAdd(&cursor[d], 1);
    eidx[p] = t;
    esrc[p] = ei[t];
  }
}

// ---------------- edge GEMM: e16 = [cos(rel*Wt+bt) | msg] @ We ----------------
// Same re-tiled MFMA core as node_gemm2. 64 edges per block, 512 threads.
__global__ __launch_bounds__(512) void edge_gemm2(
    const int* __restrict__ ei, const float* __restrict__ tvec,
    const float* __restrict__ lu, const float* __restrict__ msg,
    const float* __restrict__ Wtim, const float* __restrict__ btim,
    const short* __restrict__ WeT, unsigned short* __restrict__ e16g)
{
  __shared__ short attr[64 * 264];
  __shared__ float rel[64];

  const int tid = threadIdx.x;
  const int l = tid & 63;
  const int w = tid >> 6;
  const int e0 = blockIdx.x * 64;

  if (tid < 64) rel[tid] = tvec[e0 + tid] - lu[ei[e0 + tid]];
  // msg staging: 64 rows x 32 float4 over 512 threads (no rel dependency)
#pragma unroll
  for (int i = 0; i < 4; ++i) {
    int flat = tid + i * 512;
    int row = flat >> 5, c4 = flat & 31;
    float4 mv = *(const float4*)(msg + (size_t)(e0 + row) * 128 + c4 * 4);
    s16x4 sv; sv[0] = f2b(mv.x); sv[1] = f2b(mv.y); sv[2] = f2b(mv.z); sv[3] = f2b(mv.w);
    *(s16x4*)&attr[row * 264 + 128 + c4 * 4] = sv;
  }
  __syncthreads();   // rel ready
  // time-encoder: fixed col per thread, 16 rows each
  {
    int col = tid & 127;
    int r0 = (tid >> 7) * 16;
    float wt = Wtim[col], bt = btim[col];
#pragma unroll
    for (int i = 0; i < 16; ++i)
      attr[(r0 + i) * 264 + col] = f2b(__cosf(rel[r0 + i] * wt + bt));
  }
  __syncthreads();

  const int colb = l & 15;
  const int koff = (l >> 4) * 8;
  f32x4 acc[4][2];
#pragma unroll
  for (int m = 0; m < 4; ++m) { acc[m][0] = (f32x4)(0.0f); acc[m][1] = (f32x4)(0.0f); }

#pragma unroll
  for (int ks = 0; ks < 8; ++ks) {
    s16x8 b0 = *(const s16x8*)(WeT + (size_t)((2 * w + 0) * 16 + colb) * 256 + ks * 32 + koff);
    s16x8 b1 = *(const s16x8*)(WeT + (size_t)((2 * w + 1) * 16 + colb) * 256 + ks * 32 + koff);
#pragma unroll
    for (int m = 0; m < 4; ++m) {
      s16x8 a = *(const s16x8*)&attr[(16 * m + (l & 15)) * 264 + ks * 32 + koff];
      acc[m][0] = __builtin_amdgcn_mfma_f32_16x16x32_bf16(a, b0, acc[m][0], 0, 0, 0);
      acc[m][1] = __builtin_amdgcn_mfma_f32_16x16x32_bf16(a, b1, acc[m][1], 0, 0, 0);
    }
  }
  __syncthreads();   // all waves done reading attr
#pragma unroll
  for (int j = 0; j < 2; ++j)
#pragma unroll
    for (int m = 0; m < 4; ++m)
#pragma unroll
      for (int r = 0; r < 4; ++r)
        attr[(16 * m + (l >> 4) * 4 + r) * 264 + (2 * w + j) * 16 + colb] = f2b(acc[m][j][r]);
  __syncthreads();

  // stream e (bf16) to global, coalesced 16B stores
#pragma unroll
  for (int i = 0; i < 4; ++i) {
    int flat = tid + i * 512;
    int row = flat >> 5, cg = flat & 31;
    *(s16x8*)(e16g + (size_t)(e0 + row) * 256 + cg * 8) = *(const s16x8*)&attr[row * 264 + cg * 8];
  }
}

// ---------------- fused aggregate: one wave per dst node ----------------
__global__ __launch_bounds__(256) void aggregate_fused(
    const int* __restrict__ start, const int* __restrict__ eidx, const int* __restrict__ esrc,
    const unsigned short* __restrict__ Q16, const unsigned short* __restrict__ K16,
    const unsigned short* __restrict__ V16, const unsigned short* __restrict__ e16,
    float* __restrict__ out)
{
  const int d = blockIdx.x * 4 + (threadIdx.x >> 6);
  if (d >= N_NODES) return;
  const int lane = threadIdx.x & 63;
  const int s0 = start[d], s1 = start[d + 1];
  if (s1 <= s0) return;
  const int c0 = lane * 4;          // lanes 0-31: head 0; 32-63: head 1

  s16x4 qv = *(const s16x4*)(Q16 + (size_t)d * 256 + c0);
  const float q0 = b2f((unsigned short)qv[0]), q1 = b2f((unsigned short)qv[1]);
  const float q2 = b2f((unsigned short)qv[2]), q3 = b2f((unsigned short)qv[3]);

  float den = 0.f;
  float acc0 = 0.f, acc1 = 0.f, acc2 = 0.f, acc3 = 0.f;
  for (int p = s0; p < s1; ++p) {
    int e = eidx[p], s = esrc[p];
    s16x4 ev = *(const s16x4*)(e16 + (size_t)e * 256 + c0);
    s16x4 kv = *(const s16x4*)(K16 + (size_t)s * 256 + c0);
    s16x4 vv = *(const s16x4*)(V16 + (size_t)s * 256 + c0);
    float e0f = b2f((unsigned short)ev[0]), e1f = b2f((unsigned short)ev[1]);
    float e2f = b2f((unsigned short)ev[2]), e3f = b2f((unsigned short)ev[3]);
    float part = q0 * (b2f((unsigned short)kv[0]) + e0f)
               + q1 * (b2f((unsigned short)kv[1]) + e1f)
               + q2 * (b2f((unsigned short)kv[2]) + e2f)
               + q3 * (b2f((unsigned short)kv[3]) + e3f);
    part += __shfl_xor(part, 1);
    part += __shfl_xor(part, 2);
    part += __shfl_xor(part, 4);
    part += __shfl_xor(part, 8);
    part += __shfl_xor(part, 16);    // per-head (32-lane) total
    float ex = __expf(part * INV_SQRT_C);
    den += ex;
    acc0 += ex * (b2f((unsigned short)vv[0]) + e0f);
    acc1 += ex * (b2f((unsigned short)vv[1]) + e1f);
    acc2 += ex * (b2f((unsigned short)vv[2]) + e2f);
    acc3 += ex * (b2f((unsigned short)vv[3]) + e3f);
  }
  float inv = 1.f / (den + 1e-16f);
  float4* op = (float4*)(out + (size_t)d * 256 + c0);
  float4 o = *op;
  o.x += acc0 * inv; o.y += acc1 * inv; o.z += acc2 * inv; o.w += acc3 * inv;
  *op = o;
}

extern "C" void kernel_launch(void* const* d_in, const int* in_sizes, int n_in,
                              void* d_out, int out_size, void* d_ws, size_t ws_size,
                              hipStream_t stream) {
  const float* x_user  = (const float*)d_in[0];
  const float* x_item  = (const float*)d_in[1];
  const float* lu_user = (const float*)d_in[2];
  const float* lu_item = (const float*)d_in[3];
  const int*   ei_a    = (const int*)d_in[4];
  const int*   ei_b    = (const int*)d_in[5];
  const float* t_a     = (const float*)d_in[6];
  const float* t_b     = (const float*)d_in[7];
  const float* msg_a   = (const float*)d_in[8];
  const float* msg_b   = (const float*)d_in[9];
  const float* W_t     = (const float*)d_in[10];
  const float* b_t     = (const float*)d_in[11];
  const float* Wq_a = (const float*)d_in[12]; const float* bq_a = (const float*)d_in[13];
  const float* Wk_a = (const float*)d_in[14]; const float* bk_a = (const float*)d_in[15];
  const float* Wv_a = (const float*)d_in[16]; const float* bv_a = (const float*)d_in[17];
  const float* We_a = (const float*)d_in[18];
  const float* Ws_a = (const float*)d_in[19]; const float* bs_a = (const float*)d_in[20];
  const float* Wq_b = (const float*)d_in[21]; const float* bq_b = (const float*)d_in[22];
  const float* Wk_b = (const float*)d_in[23]; const float* bk_b = (const float*)d_in[24];
  const float* Wv_b = (const float*)d_in[25]; const float* bv_b = (const float*)d_in[26];
  const float* We_b = (const float*)d_in[27];
  const float* Ws_b = (const float*)d_in[28]; const float* bs_b = (const float*)d_in[29];

  float* out_user = (float*)d_out;
  float* out_item = (float*)d_out + (size_t)N_NODES * 256;

  WPtrs wp;
  wp.w[0] = Wq_a; wp.w[1] = Wk_a; wp.w[2] = Wv_a; wp.w[3] = Ws_a; wp.w[4] = We_a;
  wp.w[5] = Wq_b; wp.w[6] = Wk_b; wp.w[7] = Wv_b; wp.w[8] = Ws_b; wp.w[9] = We_b;

  dim3 blk(256);
  dim3 blk512(512);
  dim3 gW(80);
  dim3 gN((N_NODES + 63) / 64);
  dim3 gE(E_EDGES / 64);
  dim3 gEt((E_EDGES + 255) / 256);
  dim3 gAgg((N_NODES + 3) / 4);

  // ws layout: ~183 MB
  char* ws = (char*)d_ws;
  size_t off = 0;
  short* WtT = (short*)(ws + off); off += (size_t)10 * 65536 * 2;
  unsigned short* Q16 = (unsigned short*)(ws + off); off += (size_t)N_NODES * 256 * 2;
  unsigned short* K16 = (unsigned short*)(ws + off); off += (size_t)N_NODES * 256 * 2;
  unsigned short* V16 = (unsigned short*)(ws + off); off += (size_t)N_NODES * 256 * 2;
  unsigned short* e16 = (unsigned short*)(ws + off); off += (size_t)E_EDGES * 256 * 2;
  int* counts = (int*)(ws + off); off += (size_t)N_NODES * 4;
  int* startb = (int*)(ws + off); off += (size_t)(N_NODES + 4) * 4;
  int* cursor = (int*)(ws + off); off += (size_t)N_NODES * 4;
  int* eidx   = (int*)(ws + off); off += (size_t)E_EDGES * 4;
  int* esrc   = (int*)(ws + off); off += (size_t)E_EDGES * 4;
  if (ws_size < off) return;   // fail loudly (output stays poisoned)

  prep_transpose<<<gW, blk, 0, stream>>>(wp, WtT);

  // ---- type a: user --to--> item (dst=item) ----
  node_gemm2<<<gN, blk512, 0, stream>>>(x_user, N_NODES,
      WtT + 1 * 65536, bk_a, K16, nullptr, WtT + 2 * 65536, bv_a, V16, nullptr);
  node_gemm2<<<gN, blk512, 0, stream>>>(x_item, N_NODES,
      WtT + 0 * 65536, bq_a, Q16, nullptr, WtT + 3 * 65536, bs_a, nullptr, out_item);
  hipMemsetAsync(counts, 0, (size_t)N_NODES * 4, stream);
  csr_count<<<gEt, blk, 0, stream>>>(ei_a, counts);
  csr_scan<<<1, 1024, 0, stream>>>(counts, startb, cursor, N_NODES);
  csr_fill<<<gEt, blk, 0, stream>>>(ei_a, cursor, eidx, esrc);
  edge_gemm2<<<gE, blk512, 0, stream>>>(ei_a, t_a, lu_user, msg_a, W_t, b_t,
      WtT + 4 * 65536, e16);
  aggregate_fused<<<gAgg, blk, 0, stream>>>(startb, eidx, esrc, Q16, K16, V16, e16, out_item);

  // ---- type b: item --rev_to--> user (dst=user) ----
  node_gemm2<<<gN, blk512, 0, stream>>>(x_item, N_NODES,
      WtT + 6 * 65536, bk_b, K16, nullptr, WtT + 7 * 65536, bv_b, V16, nullptr);
  node_gemm2<<<gN, blk512, 0, stream>>>(x_user, N_NODES,
      WtT + 5 * 65536, bq_b, Q16, nullptr, WtT + 8 * 65536, bs_b, nullptr, out_user);
  hipMemsetAsync(counts, 0, (size_t)N_NODES * 4, stream);
  csr_count<<<gEt, blk, 0, stream>>>(ei_b, counts);
  csr_scan<<<1, 1024, 0, stream>>>(counts, startb, cursor, N_NODES);
  csr_fill<<<gEt, blk, 0, stream>>>(ei_b, cursor, eidx, esrc);
  edge_gemm2<<<gE, blk512, 0, stream>>>(ei_b, t_b, lu_item, msg_b, W_t, b_t,
      WtT + 9 * 65536, e16);
  aggregate_fused<<<gAgg, blk, 0, stream>>>(startb, eidx, esrc, Q16, K16, V16, e16, out_user);
}